// Round 11
// baseline (471.602 us; speedup 1.0000x reference)
//
#include <hip/hip_runtime.h>
#include <hip/hip_bf16.h>

#define HIDN 1024
#define NH   8
#define DH   128
#define BB   4
#define SS   2048

typedef __bf16 bf16;
typedef bf16 bf16x4 __attribute__((ext_vector_type(4)));
typedef bf16 bf16x8 __attribute__((ext_vector_type(8)));
typedef float f32x4 __attribute__((ext_vector_type(4)));

#if __has_builtin(__builtin_amdgcn_exp2f)
#define EXP2(x) __builtin_amdgcn_exp2f(x)
#else
#define EXP2(x) exp2f(x)
#endif

static __device__ inline f32x4 mfma16(bf16x8 a, bf16x8 b, f32x4 c) {
    return __builtin_amdgcn_mfma_f32_16x16x32_bf16(a, b, c, 0, 0, 0);
}

// async global->LDS, 16B per lane. LDS dest is wave-uniform base + lane*16.
static __device__ inline void gload_lds16(const void* g, void* l) {
    __builtin_amdgcn_global_load_lds(
        (const __attribute__((address_space(1))) unsigned int*)g,
        (__attribute__((address_space(3))) unsigned int*)l, 16, 0, 0);
}

// ---------------- q,k,v f32 -> bf16 (vectorized) -------------------------------
__global__ void cvt_kernel(const float* __restrict__ q, const float* __restrict__ k,
                           const float* __restrict__ v,
                           bf16* __restrict__ qo, bf16* __restrict__ ko, bf16* __restrict__ vo) {
    const float* src = blockIdx.y == 0 ? q : blockIdx.y == 1 ? k : v;
    bf16* dst = blockIdx.y == 0 ? qo : blockIdx.y == 1 ? ko : vo;
    const size_t n = (size_t)BB * SS * HIDN;
    for (size_t i = ((size_t)blockIdx.x * blockDim.x + threadIdx.x) * 8; i < n;
         i += (size_t)gridDim.x * blockDim.x * 8) {
        float4 a = *(const float4*)&src[i];
        float4 b = *(const float4*)&src[i + 4];
        bf16x8 o = {(bf16)a.x, (bf16)a.y, (bf16)a.z, (bf16)a.w,
                    (bf16)b.x, (bf16)b.y, (bf16)b.z, (bf16)b.w};
        *(bf16x8*)&dst[i] = o;
    }
}

// ---------------- weight convert + transpose: W[k][n] f32 -> WT[n][k] bf16 -----
__global__ void wconv_kernel(const float* __restrict__ W0, const float* __restrict__ W1,
                             const float* __restrict__ W2, const float* __restrict__ W3,
                             bf16* __restrict__ O) {
    const float* W = blockIdx.z == 0 ? W0 : blockIdx.z == 1 ? W1 : blockIdx.z == 2 ? W2 : W3;
    bf16* WT = O + (size_t)blockIdx.z * HIDN * HIDN;
    int nb = blockIdx.x * 64;
    int kb = blockIdx.y * 64;
    int t = threadIdx.x;
    __shared__ bf16 tile[64][72];
    {
        int r = t >> 2, cp = (t & 3) * 16;
        #pragma unroll
        for (int j = 0; j < 16; j += 4) {
            float4 val = *(const float4*)&W[(size_t)(kb + r) * HIDN + nb + cp + j];
            tile[r][cp + j + 0] = (bf16)val.x;
            tile[r][cp + j + 1] = (bf16)val.y;
            tile[r][cp + j + 2] = (bf16)val.z;
            tile[r][cp + j + 3] = (bf16)val.w;
        }
    }
    __syncthreads();
    {
        int n = t >> 2, kp = (t & 3) * 16;
        bf16 o[16];
        #pragma unroll
        for (int j = 0; j < 16; ++j) o[j] = tile[kp + j][n];
        #pragma unroll
        for (int j = 0; j < 2; ++j)
            *(bf16x8*)&WT[(size_t)(nb + n) * HIDN + kb + kp + j * 8] = *(bf16x8*)&o[j * 8];
    }
}

// ================= GEMM core (raw barriers, counted waits) =====================
template <int OUTMODE>
static __device__ inline void gemm_core(const bf16* __restrict__ A, const bf16* __restrict__ Bt,
                                        void* __restrict__ Cp, float alpha, char* smem) {
    int orig = blockIdx.x + blockIdx.y * gridDim.x;  // 512 wgs per z
    int virt = (orig & 7) * 64 + (orig >> 3);        // XCD-contiguous bands
    int bm = (virt & 63) * 128;
    int bn = (virt >> 6) * 128;
    int t = threadIdx.x;
    int wave = t >> 6, lane = t & 63;
    int wr = wave >> 1, wc = wave & 1;
    int lr = lane & 15, lg = lane >> 4;
    int so = wave * 1024 + lane * 16;
    f32x4 acc[4][4] = {};

    auto stage = [&](int k0, char* buf) {
        #pragma unroll
        for (int i = 0; i < 4; ++i) {
            int o = i * 4096 + so;
            int r = o >> 7, cb = o & 127;
            int cbs = cb ^ ((r & 7) << 4);           // inverse-swizzled source
            gload_lds16(&A[(size_t)(bm + r) * HIDN + k0 + (cbs >> 1)], buf + i * 4096 + wave * 1024);
            gload_lds16(&Bt[(size_t)(bn + r) * HIDN + k0 + (cbs >> 1)], buf + 16384 + i * 4096 + wave * 1024);
        }
    };
    stage(0, smem);
    for (int kt = 0; kt < 16; ++kt) {
        const char* cur = smem + (kt & 1) * 32768;
        char* nxt = smem + ((kt & 1) ^ 1) * 32768;
        asm volatile("s_waitcnt vmcnt(0)" ::: "memory");
        __builtin_amdgcn_s_barrier();
        if (kt < 15) stage((kt + 1) * 64, nxt);
        asm volatile("" ::: "memory");
        #pragma unroll
        for (int kd = 0; kd < 2; ++kd) {
            bf16x8 af[4], bfr[4];
            #pragma unroll
            for (int mi = 0; mi < 4; ++mi) {
                int row = wr * 64 + mi * 16 + lr;
                int cb = (kd * 64 + lg * 16) ^ ((row & 7) << 4);
                af[mi] = *(const bf16x8*)(cur + row * 128 + cb);
            }
            #pragma unroll
            for (int ni = 0; ni < 4; ++ni) {
                int row = wc * 64 + ni * 16 + lr;
                int cb = (kd * 64 + lg * 16) ^ ((row & 7) << 4);
                bfr[ni] = *(const bf16x8*)(cur + 16384 + row * 128 + cb);
            }
            #pragma unroll
            for (int mi = 0; mi < 4; ++mi)
                #pragma unroll
                for (int ni = 0; ni < 4; ++ni)
                    acc[mi][ni] = mfma16(af[mi], bfr[ni], acc[mi][ni]);
        }
    }
    if constexpr (OUTMODE == 2) {
        __syncthreads();
        bf16* tile_t = (bf16*)smem;   // [128][136]
        #pragma unroll
        for (int mi = 0; mi < 4; ++mi)
            #pragma unroll
            for (int ni = 0; ni < 4; ++ni) {
                bf16x4 o = {(bf16)acc[mi][ni][0], (bf16)acc[mi][ni][1],
                            (bf16)acc[mi][ni][2], (bf16)acc[mi][ni][3]};
                *(bf16x4*)&tile_t[(wc * 64 + ni * 16 + lr) * 136 + wr * 64 + mi * 16 + lg * 4] = o;
            }
        __syncthreads();
        int d = t >> 1, sh = (t & 1) * 64;
        int b = bm >> 11, h = bn >> 7;
        bf16* vvT = (bf16*)Cp;
        size_t base = ((size_t)(b * NH + h) * DH + d) * SS + (bm & 2047) + sh;
        #pragma unroll
        for (int j = 0; j < 8; ++j)
            *(bf16x8*)&vvT[base + j * 8] = *(const bf16x8*)&tile_t[d * 136 + sh + j * 8];
    } else {
        #pragma unroll
        for (int mi = 0; mi < 4; ++mi)
            #pragma unroll
            for (int ni = 0; ni < 4; ++ni)
                #pragma unroll
                for (int r = 0; r < 4; ++r) {
                    int row = bm + wr * 64 + mi * 16 + lg * 4 + r;
                    int col = bn + wc * 64 + ni * 16 + lr;
                    if constexpr (OUTMODE == 0)
                        ((bf16*)Cp)[(size_t)row * HIDN + col] = (bf16)(acc[mi][ni][r] * alpha);
                    else
                        ((float*)Cp)[(size_t)row * HIDN + col] = acc[mi][ni][r] * alpha;
                }
    }
}

__global__ __launch_bounds__(256, 2)
void proj_gemm_kernel(const bf16* __restrict__ qb, const bf16* __restrict__ kb,
                      const bf16* __restrict__ vb, const bf16* __restrict__ Wall,
                      bf16* __restrict__ qq, bf16* __restrict__ kk, bf16* __restrict__ vvT,
                      float qalpha) {
    __shared__ __align__(16) char smem[65536];
    int z = blockIdx.z;
    const bf16* Bt = Wall + (size_t)z * HIDN * HIDN;
    if (z == 2)      gemm_core<2>(vb, Bt, vvT, 1.0f, smem);
    else if (z == 1) gemm_core<0>(kb, Bt, kk, 1.0f, smem);
    else             gemm_core<0>(qb, Bt, qq, qalpha, smem);
}

__global__ __launch_bounds__(256, 2)
void out_gemm_kernel(const bf16* __restrict__ A, const bf16* __restrict__ Bt,
                     float* __restrict__ C) {
    __shared__ __align__(16) char smem[65536];
    gemm_core<1>(A, Bt, C, 1.0f, smem);
}

// 64-row K tile staging into swizzled LDS (16 KB buffer, rows of 256B)
static __device__ inline void stage64(const bf16* kb, int row0, char* buf, int wave, int lane) {
    #pragma unroll
    for (int i = 0; i < 4; ++i) {
        int o = i * 4096 + wave * 1024 + lane * 16;
        int r = o >> 8, cb = o & 255;
        int cbs = cb ^ ((r & 15) << 4);
        gload_lds16(&kb[(size_t)(row0 + r) * HIDN + (cbs >> 1)],
                    buf + i * 4096 + wave * 1024);
    }
}

static __device__ inline bf16x8 read_k(const char* Ksm, int row, int cstart_bytes) {
    int cb = cstart_bytes ^ ((row & 15) << 4);
    return *(const bf16x8*)(Ksm + row * 256 + cb);
}

// ---------------- fused attention: R6 structure, KVBLK=64, 3 blocks/CU ---------
__global__ __launch_bounds__(256, 3)
void attn_fused_kernel(const bf16* __restrict__ qq, const bf16* __restrict__ kk,
                       const bf16* __restrict__ vvT, const int* __restrict__ mask,
                       float* __restrict__ attn, bf16* __restrict__ ctx) {
    __shared__ __align__(16) char smem[51200];           // KA 16K | KB 16K | P 18K
    char* KA = smem;
    char* KB = smem + 16384;
    bf16(*P)[72] = (bf16(*)[72])(smem + 32768);          // [128][72] = 18432 B
    float* slf = (float*)(smem + 32768);                 // [2][128] overlay between loops

    int orig = blockIdx.x + blockIdx.y * gridDim.x;      // 512
    int virt = (orig & 7) * 64 + (orig >> 3);            // 4 bh-groups per XCD
    int qt = virt & 15, bh = virt >> 4;
    int b = bh >> 3, h = bh & 7;
    int t = threadIdx.x;
    int wave = t >> 6, lane = t & 63;
    int wr = wave >> 1, wc = wave & 1;
    int lr = lane & 15, lg = lane >> 4;

    const bf16* qbase = qq + (size_t)b * SS * HIDN + h * DH;
    const bf16* kbase = kk + (size_t)b * SS * HIDN + h * DH;
    const int* mbase = mask + b * SS;

    bf16x8 qf[4][4];
    #pragma unroll
    for (int mi = 0; mi < 4; ++mi)
        #pragma unroll
        for (int kd = 0; kd < 4; ++kd)
            qf[mi][kd] = *(const bf16x8*)&qbase[(size_t)(qt * 128 + wr * 64 + mi * 16 + lr) * HIDN + kd * 32 + lg * 8];

    unsigned long long mkbits = 0;
    #pragma unroll
    for (int kt = 0; kt < 32; ++kt)
        #pragma unroll
        for (int ni = 0; ni < 2; ++ni)
            mkbits |= (unsigned long long)(mbase[kt * 64 + wc * 32 + ni * 16 + lr] != 0)
                      << (kt * 2 + ni);

    // ---- loop 1: row sums in exp2 space with fixed offset 12 ----
    float l_[16] = {};
    stage64(kbase, 0, KA, wave, lane);
    for (int kt = 0; kt < 32; ++kt) {
        const char* cur = (kt & 1) ? KB : KA;
        char* nxt = (kt & 1) ? KA : KB;
        __syncthreads();                       // drains stage(kt) -> cur ready
        if (kt < 31) stage64(kbase, (kt + 1) * 64, nxt, wave, lane);
        f32x4 acc[4][2] = {};
        __builtin_amdgcn_s_setprio(1);
        #pragma unroll
        for (int kd = 0; kd < 4; ++kd) {
            bf16x8 kf[2];
            #pragma unroll
            for (int ni = 0; ni < 2; ++ni)
                kf[ni] = read_k(cur, wc * 32 + ni * 16 + lr, kd * 64 + lg * 16);
            #pragma unroll
            for (int mi = 0; mi < 4; ++mi)
                #pragma unroll
                for (int ni = 0; ni < 2; ++ni)
                    acc[mi][ni] = mfma16(qf[mi][kd], kf[ni], acc[mi][ni]);
        }
        __builtin_amdgcn_s_setprio(0);
        #pragma unroll
        for (int mi = 0; mi < 4; ++mi)
            #pragma unroll
            for (int r = 0; r < 4; ++r) {
                int s = mi * 4 + r;
                float v0 = ((mkbits >> (kt * 2 + 0)) & 1) ? -1e9f : acc[mi][0][r];
                float v1 = ((mkbits >> (kt * 2 + 1)) & 1) ? -1e9f : acc[mi][1][r];
                l_[s] += EXP2(v0 - 12.f) + EXP2(v1 - 12.f);
            }
    }

    // prefetch loop2 tile 0 into KA (kt=31 read from KB)
    stage64(kbase, 0, KA, wave, lane);

    // reduce across lr (16-lane butterfly), then across wc via LDS
    #pragma unroll
    for (int o = 1; o < 16; o <<= 1)
        #pragma unroll
        for (int s = 0; s < 16; ++s) l_[s] += __shfl_xor(l_[s], o);
    __syncthreads();                    // all loop1 K readers done
    if (lr == 0) {
        #pragma unroll
        for (int mi = 0; mi < 4; ++mi)
            #pragma unroll
            for (int r = 0; r < 4; ++r)
                slf[wc * 128 + wr * 64 + mi * 16 + lg * 4 + r] = l_[mi * 4 + r];
    }
    __syncthreads();
    float rl[16];
    #pragma unroll
    for (int mi = 0; mi < 4; ++mi)
        #pragma unroll
        for (int r = 0; r < 4; ++r) {
            int row = wr * 64 + mi * 16 + lg * 4 + r;
            rl[mi * 4 + r] = 1.0f / (slf[row] + slf[128 + row]);
        }
    __syncthreads();                    // slf reads done before P writes; KA tile0 drained

    // ---- loop 2: QK -> probs (P + attn stores from regs) -> PV ----
    f32x4 cacc[4][4] = {};
    for (int kt = 0; kt < 32; ++kt) {
        const char* cur = (kt & 1) ? KB : KA;
        char* nxt = (kt & 1) ? KA : KB;
        f32x4 acc[4][2] = {};
        __builtin_amdgcn_s_setprio(1);
        #pragma unroll
        for (int kd = 0; kd < 4; ++kd) {
            bf16x8 kf[2];
            #pragma unroll
            for (int ni = 0; ni < 2; ++ni)
                kf[ni] = read_k(cur, wc * 32 + ni * 16 + lr, kd * 64 + lg * 16);
            #pragma unroll
            for (int mi = 0; mi < 4; ++mi)
                #pragma unroll
                for (int ni = 0; ni < 2; ++ni)
                    acc[mi][ni] = mfma16(qf[mi][kd], kf[ni], acc[mi][ni]);
        }
        __builtin_amdgcn_s_setprio(0);
        #pragma unroll
        for (int mi = 0; mi < 4; ++mi)
            #pragma unroll
            for (int ni = 0; ni < 2; ++ni)
                #pragma unroll
                for (int r = 0; r < 4; ++r) {
                    float s = ((mkbits >> (kt * 2 + ni)) & 1) ? -1e9f : acc[mi][ni][r];
                    float p = EXP2(s - 12.f) * rl[mi * 4 + r];
                    int rowl = wr * 64 + mi * 16 + lg * 4 + r;
                    int coll = wc * 32 + ni * 16 + lr;
                    P[rowl][coll] = (bf16)p;
                    __builtin_nontemporal_store(
                        p, &attn[((size_t)bh * SS + qt * 128 + rowl) * SS + kt * 64 + coll]);
                }
        __syncthreads();                       // K reads + P writes done, P visible
        if (kt < 31) stage64(kbase, (kt + 1) * 64, nxt, wave, lane);   // hide under PV
        __builtin_amdgcn_s_setprio(1);
        #pragma unroll
        for (int ks = 0; ks < 2; ++ks) {
            bf16x8 pf[4], vf[4];
            #pragma unroll
            for (int mi = 0; mi < 4; ++mi)
                pf[mi] = *(const bf16x8*)&P[wr * 64 + mi * 16 + lr][ks * 32 + lg * 8];
            #pragma unroll
            for (int ni = 0; ni < 4; ++ni)
                vf[ni] = *(const bf16x8*)&vvT[((size_t)bh * DH + wc * 64 + ni * 16 + lr) * SS + kt * 64 + ks * 32 + lg * 8];
            #pragma unroll
            for (int mi = 0; mi < 4; ++mi)
                #pragma unroll
                for (int ni = 0; ni < 4; ++ni)
                    cacc[mi][ni] = mfma16(pf[mi], vf[ni], cacc[mi][ni]);
        }
        __builtin_amdgcn_s_setprio(0);
        __syncthreads();                       // drains stage(kt+1); P readers done
    }

    // ---- ctx via two-pass LDS bounce (P is half-width): coalesced bf16x8 ----
    #pragma unroll
    for (int hp = 0; hp < 2; ++hp) {
        __syncthreads();
        if (wc == hp) {
            #pragma unroll
            for (int mi = 0; mi < 4; ++mi)
                #pragma unroll
                for (int ni = 0; ni < 4; ++ni)
                    #pragma unroll
                    for (int r = 0; r < 4; ++r)
                        P[wr * 64 + mi * 16 + lg * 4 + r][ni * 16 + lr] = (bf16)cacc[mi][ni][r];
        }
        __syncthreads();
        int row = t >> 1, part = (t & 1) * 32;
        bf16* dst = ctx + ((size_t)b * SS + qt * 128 + row) * HIDN + h * DH + hp * 64 + part;
        #pragma unroll
        for (int j = 0; j < 4; ++j)
            *(bf16x8*)&dst[j * 8] = *(const bf16x8*)&P[row][part + j * 8];
    }
}

extern "C" void kernel_launch(void* const* d_in, const int* in_sizes, int n_in,
                              void* d_out, int out_size, void* d_ws, size_t ws_size,
                              hipStream_t stream) {
    const float* q = (const float*)d_in[0];
    const float* k = (const float*)d_in[1];
    const float* v = (const float*)d_in[2];
    const int* mask = (const int*)d_in[3];
    const float* Wq = (const float*)d_in[4];
    const float* Wk = (const float*)d_in[5];
    const float* Wv = (const float*)d_in[6];
    const float* Wo = (const float*)d_in[7];
    (void)in_sizes; (void)n_in; (void)out_size; (void)ws_size;

    float* outp = (float*)d_out;                       // out [B,S,HID], f32
    float* attn = outp + (size_t)BB * SS * HIDN;       // attn [B,H,S,S], f32

    char* ws = (char*)d_ws;
    size_t off = 0;
    auto alloc = [&](size_t bytes) { char* p = ws + off; off += (bytes + 255) & ~(size_t)255; return p; };
    const size_t wbytes = (size_t)HIDN * HIDN * sizeof(bf16);
    const size_t tbytes = (size_t)BB * SS * HIDN * sizeof(bf16);
    bf16* WmatT = (bf16*)alloc(4 * wbytes);            // WqT|WkT|WvT|WoT
    bf16* qbf = (bf16*)alloc(tbytes);
    bf16* kbf = (bf16*)alloc(tbytes);
    bf16* vbf = (bf16*)alloc(tbytes);
    bf16* qqb = (bf16*)alloc(tbytes);
    bf16* kkb = (bf16*)alloc(tbytes);
    bf16* vvTb = (bf16*)alloc(tbytes);
    bf16* ctxb = qbf;                                  // alias: qbf dead after q-proj
    bf16* WoT = WmatT + 3 * (size_t)HIDN * HIDN;

    dim3 blk(256);
    cvt_kernel<<<dim3(1024, 3), blk, 0, stream>>>(q, k, v, qbf, kbf, vbf);
    wconv_kernel<<<dim3(16, 16, 4), blk, 0, stream>>>(Wq, Wk, Wv, Wo, WmatT);

    // alpha_q = 1/sqrt(128) * log2(e): scores land directly in exp2 space
    const float qalpha = 0.12751744f;
    proj_gemm_kernel<<<dim3(64, 8, 3), blk, 0, stream>>>(qbf, kbf, vbf, WmatT,
                                                         qqb, kkb, vvTb, qalpha);

    attn_fused_kernel<<<dim3(16, 32), blk, 0, stream>>>(qqb, kkb, vvTb, mask, attn, ctxb);

    out_gemm_kernel<<<dim3(64, 8), blk, 0, stream>>>(ctxb, WoT, outp);
}

// Round 12
// 357.564 us; speedup vs baseline: 1.3189x; 1.3189x over previous
//
#include <hip/hip_runtime.h>
#include <hip/hip_bf16.h>

#define HIDN 1024
#define NH   8
#define DH   128
#define BB   4
#define SS   2048

typedef __bf16 bf16;
typedef bf16 bf16x4 __attribute__((ext_vector_type(4)));
typedef bf16 bf16x8 __attribute__((ext_vector_type(8)));
typedef float f32x4 __attribute__((ext_vector_type(4)));

#if __has_builtin(__builtin_amdgcn_exp2f)
#define EXP2(x) __builtin_amdgcn_exp2f(x)
#else
#define EXP2(x) exp2f(x)
#endif

static __device__ inline f32x4 mfma16(bf16x8 a, bf16x8 b, f32x4 c) {
    return __builtin_amdgcn_mfma_f32_16x16x32_bf16(a, b, c, 0, 0, 0);
}

// async global->LDS, 16B per lane. LDS dest is wave-uniform base + lane*16.
static __device__ inline void gload_lds16(const void* g, void* l) {
    __builtin_amdgcn_global_load_lds(
        (const __attribute__((address_space(1))) unsigned int*)g,
        (__attribute__((address_space(3))) unsigned int*)l, 16, 0, 0);
}

// ---------------- q,k,v f32 -> bf16 (vectorized) -------------------------------
__global__ void cvt_kernel(const float* __restrict__ q, const float* __restrict__ k,
                           const float* __restrict__ v,
                           bf16* __restrict__ qo, bf16* __restrict__ ko, bf16* __restrict__ vo) {
    const float* src = blockIdx.y == 0 ? q : blockIdx.y == 1 ? k : v;
    bf16* dst = blockIdx.y == 0 ? qo : blockIdx.y == 1 ? ko : vo;
    const size_t n = (size_t)BB * SS * HIDN;
    for (size_t i = ((size_t)blockIdx.x * blockDim.x + threadIdx.x) * 8; i < n;
         i += (size_t)gridDim.x * blockDim.x * 8) {
        float4 a = *(const float4*)&src[i];
        float4 b = *(const float4*)&src[i + 4];
        bf16x8 o = {(bf16)a.x, (bf16)a.y, (bf16)a.z, (bf16)a.w,
                    (bf16)b.x, (bf16)b.y, (bf16)b.z, (bf16)b.w};
        *(bf16x8*)&dst[i] = o;
    }
}

// ---------------- weight convert + transpose: W[k][n] f32 -> WT[n][k] bf16 -----
__global__ void wconv_kernel(const float* __restrict__ W0, const float* __restrict__ W1,
                             const float* __restrict__ W2, const float* __restrict__ W3,
                             bf16* __restrict__ O) {
    const float* W = blockIdx.z == 0 ? W0 : blockIdx.z == 1 ? W1 : blockIdx.z == 2 ? W2 : W3;
    bf16* WT = O + (size_t)blockIdx.z * HIDN * HIDN;
    int nb = blockIdx.x * 64;
    int kb = blockIdx.y * 64;
    int t = threadIdx.x;
    __shared__ bf16 tile[64][72];
    {
        int r = t >> 2, cp = (t & 3) * 16;
        #pragma unroll
        for (int j = 0; j < 16; j += 4) {
            float4 val = *(const float4*)&W[(size_t)(kb + r) * HIDN + nb + cp + j];
            tile[r][cp + j + 0] = (bf16)val.x;
            tile[r][cp + j + 1] = (bf16)val.y;
            tile[r][cp + j + 2] = (bf16)val.z;
            tile[r][cp + j + 3] = (bf16)val.w;
        }
    }
    __syncthreads();
    {
        int n = t >> 2, kp = (t & 3) * 16;
        bf16 o[16];
        #pragma unroll
        for (int j = 0; j < 16; ++j) o[j] = tile[kp + j][n];
        #pragma unroll
        for (int j = 0; j < 2; ++j)
            *(bf16x8*)&WT[(size_t)(nb + n) * HIDN + kb + kp + j * 8] = *(bf16x8*)&o[j * 8];
    }
}

// ================= GEMM core (raw barriers, counted waits) =====================
template <int OUTMODE>
static __device__ inline void gemm_core(const bf16* __restrict__ A, const bf16* __restrict__ Bt,
                                        void* __restrict__ Cp, float alpha, char* smem) {
    int orig = blockIdx.x + blockIdx.y * gridDim.x;  // 512 wgs per z
    int virt = (orig & 7) * 64 + (orig >> 3);        // XCD-contiguous bands
    int bm = (virt & 63) * 128;
    int bn = (virt >> 6) * 128;
    int t = threadIdx.x;
    int wave = t >> 6, lane = t & 63;
    int wr = wave >> 1, wc = wave & 1;
    int lr = lane & 15, lg = lane >> 4;
    int so = wave * 1024 + lane * 16;
    f32x4 acc[4][4] = {};

    auto stage = [&](int k0, char* buf) {
        #pragma unroll
        for (int i = 0; i < 4; ++i) {
            int o = i * 4096 + so;
            int r = o >> 7, cb = o & 127;
            int cbs = cb ^ ((r & 7) << 4);           // inverse-swizzled source
            gload_lds16(&A[(size_t)(bm + r) * HIDN + k0 + (cbs >> 1)], buf + i * 4096 + wave * 1024);
            gload_lds16(&Bt[(size_t)(bn + r) * HIDN + k0 + (cbs >> 1)], buf + 16384 + i * 4096 + wave * 1024);
        }
    };
    stage(0, smem);
    for (int kt = 0; kt < 16; ++kt) {
        const char* cur = smem + (kt & 1) * 32768;
        char* nxt = smem + ((kt & 1) ^ 1) * 32768;
        asm volatile("s_waitcnt vmcnt(0)" ::: "memory");
        __builtin_amdgcn_s_barrier();
        if (kt < 15) stage((kt + 1) * 64, nxt);
        asm volatile("" ::: "memory");
        #pragma unroll
        for (int kd = 0; kd < 2; ++kd) {
            bf16x8 af[4], bfr[4];
            #pragma unroll
            for (int mi = 0; mi < 4; ++mi) {
                int row = wr * 64 + mi * 16 + lr;
                int cb = (kd * 64 + lg * 16) ^ ((row & 7) << 4);
                af[mi] = *(const bf16x8*)(cur + row * 128 + cb);
            }
            #pragma unroll
            for (int ni = 0; ni < 4; ++ni) {
                int row = wc * 64 + ni * 16 + lr;
                int cb = (kd * 64 + lg * 16) ^ ((row & 7) << 4);
                bfr[ni] = *(const bf16x8*)(cur + 16384 + row * 128 + cb);
            }
            #pragma unroll
            for (int mi = 0; mi < 4; ++mi)
                #pragma unroll
                for (int ni = 0; ni < 4; ++ni)
                    acc[mi][ni] = mfma16(af[mi], bfr[ni], acc[mi][ni]);
        }
    }
    if constexpr (OUTMODE == 2) {
        __syncthreads();
        bf16* tile_t = (bf16*)smem;   // [128][136]
        #pragma unroll
        for (int mi = 0; mi < 4; ++mi)
            #pragma unroll
            for (int ni = 0; ni < 4; ++ni) {
                bf16x4 o = {(bf16)acc[mi][ni][0], (bf16)acc[mi][ni][1],
                            (bf16)acc[mi][ni][2], (bf16)acc[mi][ni][3]};
                *(bf16x4*)&tile_t[(wc * 64 + ni * 16 + lr) * 136 + wr * 64 + mi * 16 + lg * 4] = o;
            }
        __syncthreads();
        int d = t >> 1, sh = (t & 1) * 64;
        int b = bm >> 11, h = bn >> 7;
        bf16* vvT = (bf16*)Cp;
        size_t base = ((size_t)(b * NH + h) * DH + d) * SS + (bm & 2047) + sh;
        #pragma unroll
        for (int j = 0; j < 8; ++j)
            *(bf16x8*)&vvT[base + j * 8] = *(const bf16x8*)&tile_t[d * 136 + sh + j * 8];
    } else {
        #pragma unroll
        for (int mi = 0; mi < 4; ++mi)
            #pragma unroll
            for (int ni = 0; ni < 4; ++ni)
                #pragma unroll
                for (int r = 0; r < 4; ++r) {
                    int row = bm + wr * 64 + mi * 16 + lg * 4 + r;
                    int col = bn + wc * 64 + ni * 16 + lr;
                    if constexpr (OUTMODE == 0)
                        ((bf16*)Cp)[(size_t)row * HIDN + col] = (bf16)(acc[mi][ni][r] * alpha);
                    else
                        ((float*)Cp)[(size_t)row * HIDN + col] = acc[mi][ni][r] * alpha;
                }
    }
}

__global__ __launch_bounds__(256, 2)
void proj_gemm_kernel(const bf16* __restrict__ qb, const bf16* __restrict__ kb,
                      const bf16* __restrict__ vb, const bf16* __restrict__ Wall,
                      bf16* __restrict__ qq, bf16* __restrict__ kk, bf16* __restrict__ vvT,
                      float qalpha) {
    __shared__ __align__(16) char smem[65536];
    int z = blockIdx.z;
    const bf16* Bt = Wall + (size_t)z * HIDN * HIDN;
    if (z == 2)      gemm_core<2>(vb, Bt, vvT, 1.0f, smem);
    else if (z == 1) gemm_core<0>(kb, Bt, kk, 1.0f, smem);
    else             gemm_core<0>(qb, Bt, qq, qalpha, smem);
}

__global__ __launch_bounds__(256, 2)
void out_gemm_kernel(const bf16* __restrict__ A, const bf16* __restrict__ Bt,
                     float* __restrict__ C) {
    __shared__ __align__(16) char smem[65536];
    gemm_core<1>(A, Bt, C, 1.0f, smem);
}

// K-tile staging into swizzled LDS (32KB, 128 rows x 256B)
static __device__ inline void stage_k(const bf16* kbase, int kt, char* Ksm, int wave, int lane) {
    #pragma unroll
    for (int i = 0; i < 8; ++i) {
        int o = i * 4096 + wave * 1024 + lane * 16;
        int r = o >> 8, cb = o & 255;
        int cbs = cb ^ ((r & 15) << 4);
        gload_lds16(&kbase[(size_t)(kt * 128 + r) * HIDN + (cbs >> 1)],
                    Ksm + i * 4096 + wave * 1024);
    }
}

static __device__ inline bf16x8 read_k(const char* Ksm, int row, int cstart_bytes) {
    int cb = cstart_bytes ^ ((row & 15) << 4);
    return *(const bf16x8*)(Ksm + row * 256 + cb);
}

// ---------------- fused attention (R6 structure, measured best, + setprio) -----
__global__ __launch_bounds__(256, 2)
void attn_fused_kernel(const bf16* __restrict__ qq, const bf16* __restrict__ kk,
                       const bf16* __restrict__ vvT, const int* __restrict__ mask,
                       float* __restrict__ attn, bf16* __restrict__ ctx) {
    __shared__ __align__(16) char smem[67584];
    char* K0 = smem;                                     // 32KB
    char* K1 = smem + 32768;                             // loop1 dbuf (32KB)
    bf16(*P)[136] = (bf16(*)[136])(smem + 32768);        // loop2 (34816B)
    float* slf = (float*)(smem + 32768);                 // [2][128] between loops

    int orig = blockIdx.x + blockIdx.y * gridDim.x;      // 512
    int virt = (orig & 7) * 64 + (orig >> 3);            // 4 bh-groups per XCD
    int qt = virt & 15, bh = virt >> 4;
    int b = bh >> 3, h = bh & 7;
    int t = threadIdx.x;
    int wave = t >> 6, lane = t & 63;
    int wr = wave >> 1, wc = wave & 1;
    int lr = lane & 15, lg = lane >> 4;

    const bf16* qbase = qq + (size_t)b * SS * HIDN + h * DH;
    const bf16* kbase = kk + (size_t)b * SS * HIDN + h * DH;
    const int* mbase = mask + b * SS;

    bf16x8 qf[4][4];
    #pragma unroll
    for (int mi = 0; mi < 4; ++mi)
        #pragma unroll
        for (int kd = 0; kd < 4; ++kd)
            qf[mi][kd] = *(const bf16x8*)&qbase[(size_t)(qt * 128 + wr * 64 + mi * 16 + lr) * HIDN + kd * 32 + lg * 8];

    unsigned long long mkbits = 0;
    #pragma unroll
    for (int kt = 0; kt < 16; ++kt)
        #pragma unroll
        for (int ni = 0; ni < 4; ++ni)
            mkbits |= (unsigned long long)(mbase[kt * 128 + wc * 64 + ni * 16 + lr] != 0)
                      << (kt * 4 + ni);

    // ---- loop 1: row sums in exp2 space with fixed offset 12 ----
    float l_[16] = {};
    stage_k(kbase, 0, K0, wave, lane);
    for (int kt = 0; kt < 16; ++kt) {
        const char* cur = (kt & 1) ? K1 : K0;
        char* nxt = (kt & 1) ? K0 : K1;
        __syncthreads();                       // drains stage(kt) -> cur ready
        if (kt < 15) stage_k(kbase, kt + 1, nxt, wave, lane);   // overlaps compute
        f32x4 acc[4][4] = {};
        __builtin_amdgcn_s_setprio(1);
        #pragma unroll
        for (int kd = 0; kd < 4; ++kd) {
            bf16x8 kf[4];
            #pragma unroll
            for (int ni = 0; ni < 4; ++ni)
                kf[ni] = read_k(cur, wc * 64 + ni * 16 + lr, kd * 64 + lg * 16);
            #pragma unroll
            for (int mi = 0; mi < 4; ++mi)
                #pragma unroll
                for (int ni = 0; ni < 4; ++ni)
                    acc[mi][ni] = mfma16(qf[mi][kd], kf[ni], acc[mi][ni]);
        }
        __builtin_amdgcn_s_setprio(0);
        #pragma unroll
        for (int mi = 0; mi < 4; ++mi)
            #pragma unroll
            for (int r = 0; r < 4; ++r) {
                int s = mi * 4 + r;
                float v0 = ((mkbits >> (kt * 4 + 0)) & 1) ? -1e9f : acc[mi][0][r];
                float v1 = ((mkbits >> (kt * 4 + 1)) & 1) ? -1e9f : acc[mi][1][r];
                float v2 = ((mkbits >> (kt * 4 + 2)) & 1) ? -1e9f : acc[mi][2][r];
                float v3 = ((mkbits >> (kt * 4 + 3)) & 1) ? -1e9f : acc[mi][3][r];
                l_[s] += (EXP2(v0 - 12.f) + EXP2(v1 - 12.f)) + (EXP2(v2 - 12.f) + EXP2(v3 - 12.f));
            }
    }

    // prefetch loop2 tile 0 (K0's readers finished before the kt=15 barrier)
    stage_k(kbase, 0, K0, wave, lane);

    // reduce across lr (16-lane butterfly), then across wc via LDS
    #pragma unroll
    for (int o = 1; o < 16; o <<= 1)
        #pragma unroll
        for (int s = 0; s < 16; ++s) l_[s] += __shfl_xor(l_[s], o);
    __syncthreads();                    // K1(tile15) readers done before slf overwrite
    if (lr == 0) {
        #pragma unroll
        for (int mi = 0; mi < 4; ++mi)
            #pragma unroll
            for (int r = 0; r < 4; ++r)
                slf[wc * 128 + wr * 64 + mi * 16 + lg * 4 + r] = l_[mi * 4 + r];
    }
    __syncthreads();
    float rl[16];
    #pragma unroll
    for (int mi = 0; mi < 4; ++mi)
        #pragma unroll
        for (int r = 0; r < 4; ++r) {
            int row = wr * 64 + mi * 16 + lg * 4 + r;
            rl[mi * 4 + r] = 1.0f / (slf[row] + slf[128 + row]);
        }
    __syncthreads();                    // slf reads done before P writes; tile0 drained

    // ---- loop 2: probs -> P + attn stores (from regs), then PV ----
    f32x4 cacc[4][4] = {};
    for (int kt = 0; kt < 16; ++kt) {
        f32x4 acc[4][4] = {};
        __builtin_amdgcn_s_setprio(1);
        #pragma unroll
        for (int kd = 0; kd < 4; ++kd) {
            bf16x8 kf[4];
            #pragma unroll
            for (int ni = 0; ni < 4; ++ni)
                kf[ni] = read_k(K0, wc * 64 + ni * 16 + lr, kd * 64 + lg * 16);
            #pragma unroll
            for (int mi = 0; mi < 4; ++mi)
                #pragma unroll
                for (int ni = 0; ni < 4; ++ni)
                    acc[mi][ni] = mfma16(qf[mi][kd], kf[ni], acc[mi][ni]);
        }
        __builtin_amdgcn_s_setprio(0);
        #pragma unroll
        for (int mi = 0; mi < 4; ++mi)
            #pragma unroll
            for (int ni = 0; ni < 4; ++ni)
                #pragma unroll
                for (int r = 0; r < 4; ++r) {
                    float s = ((mkbits >> (kt * 4 + ni)) & 1) ? -1e9f : acc[mi][ni][r];
                    float p = EXP2(s - 12.f) * rl[mi * 4 + r];
                    int rowl = wr * 64 + mi * 16 + lg * 4 + r;
                    int coll = wc * 64 + ni * 16 + lr;
                    P[rowl][coll] = (bf16)p;
                    __builtin_nontemporal_store(
                        p, &attn[((size_t)bh * SS + qt * 128 + rowl) * SS + kt * 128 + coll]);
                }
        __syncthreads();                       // K reads + P writes done, P visible
        if (kt < 15) stage_k(kbase, kt + 1, K0, wave, lane);   // hide under PV
        __builtin_amdgcn_s_setprio(1);
        #pragma unroll
        for (int ks = 0; ks < 4; ++ks) {
            bf16x8 pf[4], vf[4];
            #pragma unroll
            for (int mi = 0; mi < 4; ++mi)
                pf[mi] = *(const bf16x8*)&P[wr * 64 + mi * 16 + lr][ks * 32 + lg * 8];
            #pragma unroll
            for (int ni = 0; ni < 4; ++ni)
                vf[ni] = *(const bf16x8*)&vvT[((size_t)bh * DH + wc * 64 + ni * 16 + lr) * SS + kt * 128 + ks * 32 + lg * 8];
            #pragma unroll
            for (int mi = 0; mi < 4; ++mi)
                #pragma unroll
                for (int ni = 0; ni < 4; ++ni)
                    cacc[mi][ni] = mfma16(pf[mi], vf[ni], cacc[mi][ni]);
        }
        __builtin_amdgcn_s_setprio(0);
        __syncthreads();                       // drains stage(kt+1); P readers done
    }

    // ---- ctx via LDS bounce: 64 scalar stores -> 8x bf16x8 coalesced ----
    #pragma unroll
    for (int mi = 0; mi < 4; ++mi)
        #pragma unroll
        for (int ni = 0; ni < 4; ++ni)
            #pragma unroll
            for (int r = 0; r < 4; ++r)
                P[wr * 64 + mi * 16 + lg * 4 + r][wc * 64 + ni * 16 + lr] = (bf16)cacc[mi][ni][r];
    __syncthreads();
    {
        int row = t >> 1, half = (t & 1) * 64;
        bf16* dst = ctx + ((size_t)b * SS + qt * 128 + row) * HIDN + h * DH + half;
        #pragma unroll
        for (int j = 0; j < 8; ++j)
            *(bf16x8*)&dst[j * 8] = *(const bf16x8*)&P[row][half + j * 8];
    }
}

extern "C" void kernel_launch(void* const* d_in, const int* in_sizes, int n_in,
                              void* d_out, int out_size, void* d_ws, size_t ws_size,
                              hipStream_t stream) {
    const float* q = (const float*)d_in[0];
    const float* k = (const float*)d_in[1];
    const float* v = (const float*)d_in[2];
    const int* mask = (const int*)d_in[3];
    const float* Wq = (const float*)d_in[4];
    const float* Wk = (const float*)d_in[5];
    const float* Wv = (const float*)d_in[6];
    const float* Wo = (const float*)d_in[7];
    (void)in_sizes; (void)n_in; (void)out_size; (void)ws_size;

    float* outp = (float*)d_out;                       // out [B,S,HID], f32
    float* attn = outp + (size_t)BB * SS * HIDN;       // attn [B,H,S,S], f32

    char* ws = (char*)d_ws;
    size_t off = 0;
    auto alloc = [&](size_t bytes) { char* p = ws + off; off += (bytes + 255) & ~(size_t)255; return p; };
    const size_t wbytes = (size_t)HIDN * HIDN * sizeof(bf16);
    const size_t tbytes = (size_t)BB * SS * HIDN * sizeof(bf16);
    bf16* WmatT = (bf16*)alloc(4 * wbytes);            // WqT|WkT|WvT|WoT
    bf16* qbf = (bf16*)alloc(tbytes);
    bf16* kbf = (bf16*)alloc(tbytes);
    bf16* vbf = (bf16*)alloc(tbytes);
    bf16* qqb = (bf16*)alloc(tbytes);
    bf16* kkb = (bf16*)alloc(tbytes);
    bf16* vvTb = (bf16*)alloc(tbytes);
    bf16* ctxb = qbf;                                  // alias: qbf dead after q-proj
    bf16* WoT = WmatT + 3 * (size_t)HIDN * HIDN;

    dim3 blk(256);
    cvt_kernel<<<dim3(1024, 3), blk, 0, stream>>>(q, k, v, qbf, kbf, vbf);
    wconv_kernel<<<dim3(16, 16, 4), blk, 0, stream>>>(Wq, Wk, Wv, Wo, WmatT);

    // alpha_q = 1/sqrt(128) * log2(e): scores land directly in exp2 space
    const float qalpha = 0.12751744f;
    proj_gemm_kernel<<<dim3(64, 8, 3), blk, 0, stream>>>(qbf, kbf, vbf, WmatT,
                                                         qqb, kkb, vvTb, qalpha);

    attn_fused_kernel<<<dim3(16, 32), blk, 0, stream>>>(qqb, kkb, vvTb, mask, attn, ctxb);

    out_gemm_kernel<<<dim3(64, 8), blk, 0, stream>>>(ctxb, WoT, outp);
}